// Round 2
// baseline (394.910 us; speedup 1.0000x reference)
//
#include <hip/hip_runtime.h>
#include <stdint.h>

#define NN 100000      // nodes
#define NE 1600000     // edges
#define MAXDEG 64      // Poisson(16): P(deg>64) ~ 1e-19, safe cap
#define NSLICE 8       // XCD count; slice = blockIdx & 7 (perf heuristic only)
#define SLICE_SZ 12500 // nodes per slice
#define CHUNK 6400     // edges per block; NE/CHUNK = 250 chunks per slice

typedef __attribute__((ext_vector_type(8))) short short8;
typedef __attribute__((ext_vector_type(4))) float f32x4;

__device__ __forceinline__ float bflo(unsigned v) { return __uint_as_float(v << 16); }
__device__ __forceinline__ float bfhi(unsigned v) { return __uint_as_float(v & 0xffff0000u); }
__device__ __forceinline__ unsigned short f2bf(float f) {   // round-to-nearest-even
  unsigned u = __float_as_uint(f);
  u += 0x7fff + ((u >> 16) & 1);
  return (unsigned short)(u >> 16);
}

// ---- XCD-sliced bucket build: per-XCD write region 3.2MB -> L2-resident ----
__global__ __launch_bounds__(256) void build_buckets(const int* __restrict__ src,
                                                     const int* __restrict__ dst,
                                                     int* __restrict__ cnt,
                                                     int* __restrict__ buck) {
  const int slice = blockIdx.x & (NSLICE - 1);
  const int chunk = blockIdx.x >> 3;
  const int c0 = chunk * CHUNK;
  const int lo = slice * SLICE_SZ, hi = lo + SLICE_SZ;
  for (int e = c0 + (int)threadIdx.x * 4; e < c0 + CHUNK; e += 1024) {
    int4 d = *(const int4*)(dst + e);
    int4 s = *(const int4*)(src + e);
    if (d.x >= lo && d.x < hi) { int p = atomicAdd(&cnt[d.x], 1); if (p < MAXDEG) buck[d.x * MAXDEG + p] = s.x; }
    if (d.y >= lo && d.y < hi) { int p = atomicAdd(&cnt[d.y], 1); if (p < MAXDEG) buck[d.y * MAXDEG + p] = s.y; }
    if (d.z >= lo && d.z < hi) { int p = atomicAdd(&cnt[d.z], 1); if (p < MAXDEG) buck[d.z * MAXDEG + p] = s.z; }
    if (d.w >= lo && d.w < hi) { int p = atomicAdd(&cnt[d.w], 1); if (p < MAXDEG) buck[d.w * MAXDEG + p] = s.w; }
  }
}

// ---- f32 -> packed bf16x2 (float4 per thread) ----
__global__ __launch_bounds__(256) void to_bf16(const float* __restrict__ x,
                                               unsigned* __restrict__ xb) {
  int i = blockIdx.x * 256 + threadIdx.x;     // over NN*32
  if (i >= NN * 32) return;
  float4 v = ((const float4*)x)[i];
  uint2 o;
  o.x = ((unsigned)f2bf(v.y) << 16) | f2bf(v.x);
  o.y = ((unsigned)f2bf(v.w) << 16) | f2bf(v.z);
  ((uint2*)xb)[i] = o;
}

// ---- one-time W transpose -> k-major bf16: WT[m][k], k = [Wl rows | Wr rows] ----
__global__ __launch_bounds__(256) void transpose_w(const float* __restrict__ W1l,
                                                   const float* __restrict__ W1r,
                                                   const float* __restrict__ W2l,
                                                   const float* __restrict__ W2r,
                                                   unsigned short* __restrict__ WT1,
                                                   unsigned short* __restrict__ WT2) {
  int t = blockIdx.x * 256 + threadIdx.x;
  if (t < 128 * 256) {
    int m = t >> 8, k = t & 255;
    float v = (k < 128) ? W1l[k * 128 + m] : W1r[(k - 128) * 128 + m];
    WT1[t] = f2bf(v);
  } else {
    int i = t - 128 * 256;
    if (i < 64 * 256) {
      int m = i >> 8, k = i & 255;
      float v = (k < 128) ? W2l[k * 64 + m] : W2r[(k - 128) * 64 + m];
      WT2[i] = f2bf(v);
    }
  }
}

// ---- FUSED layer: gather-mean into wave-private LDS rows, then MFMA. v3:
// the gather is restructured for MEMORY-LEVEL PARALLELISM (v2 post-mortem:
// latency-bound, only 8 small loads in flight). Now: uint4 loads with 16
// lanes/edge (4 edges/instr), 2 dest rows per batch, 32-edge chunk -> up to
// 16x 1KB loads issued back-to-back into registers BEFORE any accumulate
// (16KB in flight/wave, 4x v2). P(deg>32)~1e-4 -> one chunk covers ~all
// rows; uniform branch skips edges 16..31 when both rows have deg<=16;
// rare deg>32 tail loops per row. Clamped duplicate edges produce identical
// addresses within one instruction -> coalescer merges (no extra traffic).
template <int M, bool RELU, typename OutT>
__global__ __launch_bounds__(256) void sage_fused(const unsigned* __restrict__ xb,
                                                  const int* __restrict__ cnt,
                                                  const int* __restrict__ buck,
                                                  const unsigned short* __restrict__ WT,
                                                  const float* __restrict__ bias,
                                                  OutT* __restrict__ out) {
  __shared__ unsigned short sA[64][136];         // 272B pitch; 17408 B total

  const int t = threadIdx.x;
  const int lane = t & 63;
  const int wv = t >> 6;
  const int node0 = blockIdx.x * 64;
  const int nb = node0 + wv * 16;                // this wave's 16 nodes
  const int sub = lane >> 4;                     // edge subgroup 0..3 (4 edges/load)
  const int cl  = lane & 15;                     // 16B chunk within 256B row

  // ---- prefetch: 16 bucket rows + 16 degrees (independent loads) ----
  int slot[16]; int deg[16];
#pragma unroll
  for (int i = 0; i < 16; i++) {
    int node = nb + i;
    if (node < NN) {                             // lane-uniform branch
      slot[i] = buck[(size_t)node * MAXDEG + lane];
      deg[i]  = cnt[node];
    } else { slot[i] = 0; deg[i] = 0; }
  }
  // sanitize: deg==0 rows have garbage bucket entries; clamp picks lane 0
#pragma unroll
  for (int i = 0; i < 16; i++)
    if (deg[i] == 0) slot[i] = 0;

  // ---- gather-mean, 2 rows per batch, high-MLP ----
#define ACC8(a, v, q, d)                                                     \
  {                                                                          \
    bool ok = (4 * (q) + sub) < (d);                                         \
    unsigned w0 = ok ? (v).x : 0u, w1 = ok ? (v).y : 0u;                     \
    unsigned w2 = ok ? (v).z : 0u, w3 = ok ? (v).w : 0u;                     \
    a[0] += bflo(w0); a[1] += bfhi(w0); a[2] += bflo(w1); a[3] += bfhi(w1);  \
    a[4] += bflo(w2); a[5] += bfhi(w2); a[6] += bflo(w3); a[7] += bfhi(w3);  \
  }

#pragma unroll
  for (int b = 0; b < 8; b++) {
    const int i0 = 2 * b, i1 = 2 * b + 1;
    const int dr0 = deg[i0], dr1 = deg[i1];          // raw (uncapped) for mean
    const int d0 = dr0 < MAXDEG ? dr0 : MAXDEG;
    const int d1 = dr1 < MAXDEG ? dr1 : MAXDEG;
    const int l0 = d0 > 1 ? d0 - 1 : 0;
    const int l1 = d1 > 1 ? d1 - 1 : 0;

    uint4 v0[8], v1[8];
    // issue phase: edges 0..15 of both rows (8 x 1KB loads, no use yet)
#pragma unroll
    for (int q = 0; q < 4; q++) {
      int s = __shfl(slot[i0], min(4 * q + sub, l0), 64);
      v0[q] = *(const uint4*)(xb + (size_t)s * 64 + cl * 4);
    }
#pragma unroll
    for (int q = 0; q < 4; q++) {
      int s = __shfl(slot[i1], min(4 * q + sub, l1), 64);
      v1[q] = *(const uint4*)(xb + (size_t)s * 64 + cl * 4);
    }
    const bool big = (d0 > 16) | (d1 > 16);          // wave-uniform
    if (big) {                                       // edges 16..31
#pragma unroll
      for (int q = 4; q < 8; q++) {
        int s = __shfl(slot[i0], min(4 * q + sub, l0), 64);
        v0[q] = *(const uint4*)(xb + (size_t)s * 64 + cl * 4);
      }
#pragma unroll
      for (int q = 4; q < 8; q++) {
        int s = __shfl(slot[i1], min(4 * q + sub, l1), 64);
        v1[q] = *(const uint4*)(xb + (size_t)s * 64 + cl * 4);
      }
    }

    // accumulate phase (row1's loads stay in flight while row0 accumulates)
    float a0[8] = {0.f, 0.f, 0.f, 0.f, 0.f, 0.f, 0.f, 0.f};
    float a1[8] = {0.f, 0.f, 0.f, 0.f, 0.f, 0.f, 0.f, 0.f};
#pragma unroll
    for (int q = 0; q < 4; q++) ACC8(a0, v0[q], q, d0);
#pragma unroll
    for (int q = 0; q < 4; q++) ACC8(a1, v1[q], q, d1);
    if (big) {
#pragma unroll
      for (int q = 4; q < 8; q++) ACC8(a0, v0[q], q, d0);
#pragma unroll
      for (int q = 4; q < 8; q++) ACC8(a1, v1[q], q, d1);
    }
    // rare tail: deg > 32 (P ~ 1e-4 per row)
    if (d0 > 32) {
      for (int p = 32; p < d0; p += 16) {
#pragma unroll
        for (int q = 0; q < 4; q++) {
          int idx = p + 4 * q + sub;
          int s = __shfl(slot[i0], idx < l0 ? idx : l0, 64);
          uint4 v = *(const uint4*)(xb + (size_t)s * 64 + cl * 4);
          bool ok = idx < d0;
          unsigned w0 = ok ? v.x : 0u, w1 = ok ? v.y : 0u;
          unsigned w2 = ok ? v.z : 0u, w3 = ok ? v.w : 0u;
          a0[0] += bflo(w0); a0[1] += bfhi(w0); a0[2] += bflo(w1); a0[3] += bfhi(w1);
          a0[4] += bflo(w2); a0[5] += bfhi(w2); a0[6] += bflo(w3); a0[7] += bfhi(w3);
        }
      }
    }
    if (d1 > 32) {
      for (int p = 32; p < d1; p += 16) {
#pragma unroll
        for (int q = 0; q < 4; q++) {
          int idx = p + 4 * q + sub;
          int s = __shfl(slot[i1], idx < l1 ? idx : l1, 64);
          uint4 v = *(const uint4*)(xb + (size_t)s * 64 + cl * 4);
          bool ok = idx < d1;
          unsigned w0 = ok ? v.x : 0u, w1 = ok ? v.y : 0u;
          unsigned w2 = ok ? v.z : 0u, w3 = ok ? v.w : 0u;
          a1[0] += bflo(w0); a1[1] += bfhi(w0); a1[2] += bflo(w1); a1[3] += bfhi(w1);
          a1[4] += bflo(w2); a1[5] += bfhi(w2); a1[6] += bflo(w3); a1[7] += bfhi(w3);
        }
      }
    }

    // merge the 4 edge subgroups (lanes l, l^16, l^32 hold same channels)
#pragma unroll
    for (int k = 0; k < 8; k++) {
      a0[k] += __shfl_xor(a0[k], 16, 64);
      a0[k] += __shfl_xor(a0[k], 32, 64);
      a1[k] += __shfl_xor(a1[k], 16, 64);
      a1[k] += __shfl_xor(a1[k], 32, 64);
    }
    const float inv0 = 1.f / (float)(dr0 > 1 ? dr0 : 1);
    const float inv1 = 1.f / (float)(dr1 > 1 ? dr1 : 1);
    if (sub == 0) {                                  // 16 lanes cover the row
      uint4 o0, o1;
      o0.x = ((unsigned)f2bf(a0[1] * inv0) << 16) | f2bf(a0[0] * inv0);
      o0.y = ((unsigned)f2bf(a0[3] * inv0) << 16) | f2bf(a0[2] * inv0);
      o0.z = ((unsigned)f2bf(a0[5] * inv0) << 16) | f2bf(a0[4] * inv0);
      o0.w = ((unsigned)f2bf(a0[7] * inv0) << 16) | f2bf(a0[6] * inv0);
      *(uint4*)((unsigned short*)&sA[wv * 16 + i0][0] + cl * 8) = o0;
      o1.x = ((unsigned)f2bf(a1[1] * inv1) << 16) | f2bf(a1[0] * inv1);
      o1.y = ((unsigned)f2bf(a1[3] * inv1) << 16) | f2bf(a1[2] * inv1);
      o1.z = ((unsigned)f2bf(a1[5] * inv1) << 16) | f2bf(a1[4] * inv1);
      o1.w = ((unsigned)f2bf(a1[7] * inv1) << 16) | f2bf(a1[6] * inv1);
      *(uint4*)((unsigned short*)&sA[wv * 16 + i1][0] + cl * 8) = o1;
    }
  }
#undef ACC8

  // ---- MFMA: A from my LDS rows, B from k-major WT in global (L2-hot) ----
  const int m = lane & 15;
  const int q = lane >> 4;

  f32x4 acc[M / 16];
#pragma unroll
  for (int cc = 0; cc < M / 16; cc++) acc[cc] = {0.f, 0.f, 0.f, 0.f};

  // issue x-row loads now; latency hides under MFMA half-A
  unsigned xr[16];
#pragma unroll
  for (int i = 0; i < 16; i++) {
    int node = nb + i;
    xr[i] = (node < NN) ? xb[(size_t)node * 64 + lane] : 0u;
  }

  // half A: k in [0,128) -> agg @ Wl-rows
#pragma unroll
  for (int ks = 0; ks < 4; ks++) {
    short8 a = *(const short8*)&sA[wv * 16 + m][ks * 32 + q * 8];
#pragma unroll
    for (int cc = 0; cc < M / 16; cc++) {
      short8 b = *(const short8*)(WT + (size_t)(cc * 16 + m) * 256 + ks * 32 + q * 8);
      acc[cc] = __builtin_amdgcn_mfma_f32_16x16x32_bf16(a, b, acc[cc], 0, 0, 0);
    }
  }

  // overwrite my rows with x (per-wave LDS ordering makes read->write safe)
#pragma unroll
  for (int i = 0; i < 16; i++)
    ((unsigned*)&sA[wv * 16 + i][0])[lane] = xr[i];

  // half B: k in [128,256) -> x @ Wr-rows (accumulator carries)
#pragma unroll
  for (int ks = 4; ks < 8; ks++) {
    short8 a = *(const short8*)&sA[wv * 16 + m][(ks - 4) * 32 + q * 8];
#pragma unroll
    for (int cc = 0; cc < M / 16; cc++) {
      short8 b = *(const short8*)(WT + (size_t)(cc * 16 + m) * 256 + ks * 32 + q * 8);
      acc[cc] = __builtin_amdgcn_mfma_f32_16x16x32_bf16(a, b, acc[cc], 0, 0, 0);
    }
  }

  // ---- epilogue: restage C through my (dead) sA rows -> full-line stores ----
#pragma unroll
  for (int cc = 0; cc < M / 16; cc++) {
    int col = cc * 16 + m;
    float bc = bias[col];
#pragma unroll
    for (int r = 0; r < 4; r++) {
      int lr = wv * 16 + q * 4 + r;               // D[row=q*4+r][col=m]
      float v = acc[cc][r] + bc;
      if (RELU) v = fmaxf(v, 0.f);
      if constexpr (sizeof(OutT) == 2) sA[lr][col] = f2bf(v);
      else ((float*)&sA[lr][0])[col] = v;
    }
  }
#pragma unroll
  for (int it = 0; it < 4; it++) {
    int idx = it * 64 + lane;                     // 16 rows x 16 chunks of 16B
    int rr = idx >> 4, ck = idx & 15;
    int node = node0 + wv * 16 + rr;
    if (node < NN) {
      uint4 v = *(const uint4*)((const char*)&sA[wv * 16 + rr][0] + ck * 16);
      *(uint4*)((char*)(out + (size_t)node * M) + ck * 16) = v;
    }
  }
}

extern "C" void kernel_launch(void* const* d_in, const int* in_sizes, int n_in,
                              void* d_out, int out_size, void* d_ws, size_t ws_size,
                              hipStream_t stream) {
  const float* x   = (const float*)d_in[0];
  const int*   ei  = (const int*)d_in[1];
  const float* W1l = (const float*)d_in[2];
  const float* b1  = (const float*)d_in[3];
  const float* W1r = (const float*)d_in[4];
  const float* W2l = (const float*)d_in[5];
  const float* b2  = (const float*)d_in[6];
  const float* W2r = (const float*)d_in[7];
  float* out = (float*)d_out;

  // ws: cnt 0.5MB | buck 25.6MB | xbf 12.8MB | h 12.8MB | WT1 | WT2
  char* ws = (char*)d_ws;
  int* cnt  = (int*)ws;                                   ws += (512 << 10);
  int* buck = (int*)ws;                                   ws += (size_t)NN * MAXDEG * 4;
  unsigned* xbf = (unsigned*)ws;                          ws += (size_t)NN * 64 * 4;
  unsigned* hb = (unsigned*)ws;                           ws += (size_t)NN * 64 * 4;
  unsigned short* WT1 = (unsigned short*)ws;              ws += 128 * 256 * 2;
  unsigned short* WT2 = (unsigned short*)ws;              ws += 64 * 256 * 2;

  const int* src = ei;        // edge_index[0]
  const int* dst = ei + NE;   // edge_index[1]

  hipMemsetAsync(cnt, 0, (size_t)NN * 4, stream);
  build_buckets<<<NSLICE * (NE / CHUNK), 256, 0, stream>>>(src, dst, cnt, buck);
  to_bf16<<<(NN * 32 + 255) / 256, 256, 0, stream>>>(x, xbf);
  transpose_w<<<192, 256, 0, stream>>>(W1l, W1r, W2l, W2r, WT1, WT2);

  // layer 1: h = relu([mean|x] @ [W1l;W1r] + b1), bf16
  sage_fused<128, true, unsigned short><<<(NN + 63) / 64, 256, 0, stream>>>(
      xbf, cnt, buck, WT1, b1, (unsigned short*)hb);

  // layer 2: out = [mean|h] @ [W2l;W2r] + b2, f32
  sage_fused<64, false, float><<<(NN + 63) / 64, 256, 0, stream>>>(
      hb, cnt, buck, WT2, b2, out);
}